// Round 1
// baseline (215.839 us; speedup 1.0000x reference)
//
#include <hip/hip_runtime.h>
#include <stdint.h>

// Segmented kNN graph: M=65536 pts, D=16, 64 segments x 1024 pts, K=16.
// Output: int32 src[M*K] then int32 dst[M*K].
#define M_PTS 65536
#define D_DIM 16
#define L_SEG 1024
#define KNN   16

__device__ __forceinline__ uint32_t umin32(uint32_t a, uint32_t b) { return a < b ? a : b; }
__device__ __forceinline__ uint32_t umax32(uint32_t a, uint32_t b) { return a > b ? a : b; }

__device__ __forceinline__ float d2part(float4 q, float4 c, float acc) {
    float t0 = q.x - c.x; acc = __builtin_fmaf(t0, t0, acc);
    float t1 = q.y - c.y; acc = __builtin_fmaf(t1, t1, acc);
    float t2 = q.z - c.z; acc = __builtin_fmaf(t2, t2, acc);
    float t3 = q.w - c.w; acc = __builtin_fmaf(t3, t3, acc);
    return acc;
}

__global__ __launch_bounds__(256) void knn_seg_kernel(const float* __restrict__ x,
                                                      int* __restrict__ out) {
    // 64 KB LDS: one segment's 1024 points x 16 floats
    __shared__ float4 sx[L_SEG * 4];

    const int tid  = threadIdx.x;
    const int b    = blockIdx.x;
    const int seg  = b >> 2;                  // 4 blocks per segment
    const int qloc = ((b & 3) << 8) | tid;    // 0..1023 query within segment

    // Stage segment coords (coalesced float4 loads)
    const float4* gx = (const float4*)(x + (size_t)seg * (L_SEG * D_DIM));
    #pragma unroll
    for (int i = 0; i < 16; ++i)
        sx[tid + 256 * i] = gx[tid + 256 * i];
    __syncthreads();

    // Query coords in registers
    const float4 q0 = sx[qloc * 4 + 0];
    const float4 q1 = sx[qloc * 4 + 1];
    const float4 q2 = sx[qloc * 4 + 2];
    const float4 q3 = sx[qloc * 4 + 3];

    // Top-16 as packed keys: high 22 bits = d2 float bits, low 10 = candidate idx.
    // Sorted ascending; key compare == (d2, idx) lexicographic (stable ties).
    uint32_t a[KNN];
    #pragma unroll
    for (int i = 0; i < KNN; ++i) a[i] = 0xFFFFFFFFu;

    for (int j = 0; j < L_SEG; j += 2) {
        const float4 c0 = sx[j * 4 + 0];
        const float4 c1 = sx[j * 4 + 1];
        const float4 c2 = sx[j * 4 + 2];
        const float4 c3 = sx[j * 4 + 3];
        const float4 e0 = sx[j * 4 + 4];
        const float4 e1 = sx[j * 4 + 5];
        const float4 e2 = sx[j * 4 + 6];
        const float4 e3 = sx[j * 4 + 7];

        // Two independent distance chains per candidate (ILP)
        float d0 = d2part(q2, c2, d2part(q0, c0, 0.0f)) +
                   d2part(q3, c3, d2part(q1, c1, 0.0f));
        float d1 = d2part(q2, e2, d2part(q0, e0, 0.0f)) +
                   d2part(q3, e3, d2part(q1, e1, 0.0f));

        const uint32_t k0 = (__float_as_uint(d0) & 0xFFFFFC00u) | (uint32_t)j;
        const uint32_t k1 = (__float_as_uint(d1) & 0xFFFFFC00u) | (uint32_t)(j + 1);

        if (umin32(k0, k1) < a[KNN - 1]) {
            // Insert k0: min/max bubble keeps array sorted, drops the max
            uint32_t v = k0;
            #pragma unroll
            for (int i = 0; i < KNN; ++i) {
                uint32_t lo = umin32(v, a[i]);
                uint32_t hi = umax32(v, a[i]);
                a[i] = lo; v = hi;
            }
            v = k1;
            #pragma unroll
            for (int i = 0; i < KNN; ++i) {
                uint32_t lo = umin32(v, a[i]);
                uint32_t hi = umax32(v, a[i]);
                a[i] = lo; v = hi;
            }
        }
    }

    // Epilogue: src = seg_base + local_idx (sorted ascending by distance), dst = query id
    const int base = seg * L_SEG;
    const int qg   = base + qloc;

    int4* osrc = (int4*)out + (size_t)qg * 4;
    #pragma unroll
    for (int i = 0; i < 4; ++i) {
        int4 r;
        r.x = base + (int)(a[4 * i + 0] & 1023u);
        r.y = base + (int)(a[4 * i + 1] & 1023u);
        r.z = base + (int)(a[4 * i + 2] & 1023u);
        r.w = base + (int)(a[4 * i + 3] & 1023u);
        osrc[i] = r;
    }

    int4* odst = (int4*)out + (size_t)M_PTS * 4 + (size_t)qg * 4;
    const int4 dd = make_int4(qg, qg, qg, qg);
    #pragma unroll
    for (int i = 0; i < 4; ++i) odst[i] = dd;
}

extern "C" void kernel_launch(void* const* d_in, const int* in_sizes, int n_in,
                              void* d_out, int out_size, void* d_ws, size_t ws_size,
                              hipStream_t stream) {
    const float* x = (const float*)d_in[0];
    // d_in[1] = segs (int64, all 1024) — static per problem setup, unused.
    int* out = (int*)d_out;
    knn_seg_kernel<<<dim3(256), dim3(256), 0, stream>>>(x, out);
}

// Round 2
// 100.954 us; speedup vs baseline: 2.1380x; 2.1380x over previous
//
#include <hip/hip_runtime.h>
#include <stdint.h>

// Segmented kNN graph: M=65536 pts, D=16, 64 segments x 1024 pts, K=16.
// Output: int32 src[M*16] then int32 dst[M*16].
//
// Strategy: per segment, scores = -2*Q.C^T via mfma_f32_16x16x32_f16 (K zero-
// padded 16->32), candidates as A rows, queries as B cols. D-layout
// (col=lane&15,row=4*(lane>>4)+reg) => each lane owns ONE query and gets 4
// candidate scores per tile in registers. Top-16 kept as packed sortable keys
// (monotone float bits | 10-bit cand idx), maintained by batched bitonic
// sort-16 + merge (15 ops/cand, wide ILP) instead of a serial bubble insert.

#define L_SEG 1024
#define M_PTS 65536

typedef _Float16 half8 __attribute__((ext_vector_type(8)));
typedef _Float16 half4h __attribute__((ext_vector_type(4)));
typedef float f32x4 __attribute__((ext_vector_type(4)));

__device__ __forceinline__ uint32_t umn(uint32_t a, uint32_t b) { return a < b ? a : b; }
__device__ __forceinline__ uint32_t umx(uint32_t a, uint32_t b) { return a > b ? a : b; }

__global__ __launch_bounds__(256, 4) void knn_mfma_kernel(const float* __restrict__ x,
                                                          int* __restrict__ out) {
    // LDS: [0,32768) f16 coords [1024][16]; [32768,36864) fp32 |c|^2; [36864,36880) zero pad
    __shared__ __attribute__((aligned(16))) char smem[36880];
    _Float16* sc  = (_Float16*)smem;
    float*    ssq = (float*)(smem + 32768);

    const int tid = threadIdx.x;
    const int b   = blockIdx.x;
    // XCD swizzle: XCD x (b&7) handles segments 8x..8x+7 -> staging L2-resident
    const int seg = (b & 7) * 8 + (b >> 7);
    const int qb  = (b >> 3) & 15;  // query-quarter... 1/16th of segment (64 queries)

    if (tid < 4) ((uint32_t*)(smem + 36864))[tid] = 0u;

    // ---- Stage segment coords as f16 (coalesced) ----
    const f32x4* gx  = (const f32x4*)(x + (size_t)seg * (L_SEG * 16));
    half4h*      scv = (half4h*)sc;
    #pragma unroll
    for (int i = 0; i < 16; ++i) {
        f32x4 v = gx[tid + 256 * i];
        half4h h;
        h[0] = (_Float16)v[0]; h[1] = (_Float16)v[1];
        h[2] = (_Float16)v[2]; h[3] = (_Float16)v[3];
        scv[tid + 256 * i] = h;
    }
    __syncthreads();

    // ---- |c|^2 from the f16-quantized coords (consistent with MFMA dots) ----
    {
        const int c0 = tid * 4;
        #pragma unroll
        for (int c = 0; c < 4; ++c) {
            const half8* hp = (const half8*)(sc + (size_t)(c0 + c) * 16);
            half8 h0 = hp[0], h1 = hp[1];
            float s = 0.f;
            #pragma unroll
            for (int j = 0; j < 8; ++j) { float f = (float)h0[j]; s = __builtin_fmaf(f, f, s); }
            #pragma unroll
            for (int j = 0; j < 8; ++j) { float f = (float)h1[j]; s = __builtin_fmaf(f, f, s); }
            ssq[c0 + c] = s;
        }
    }
    __syncthreads();

    const int lane = tid & 63;
    const int wv   = tid >> 6;
    const int g    = lane >> 4;   // k-quad / row-group
    const int col  = lane & 15;   // this lane's query (D col)
    const int qloc = qb * 64 + wv * 16 + col;

    // B fragment (queries), loaded once. Lanes g>=2 supply the zero k-pad.
    const char* bsrc = (g < 2) ? ((const char*)sc + (size_t)qloc * 32 + g * 16)
                               : (const char*)(smem + 36864);
    const half8 bfrag = *(const half8*)bsrc;

    // A fragment stream (candidate tiles): advance 512B/tile (0 for pad lanes)
    const char* aptr  = (g < 2) ? ((const char*)sc + (size_t)col * 32 + g * 16)
                                : (const char*)(smem + 36864);
    const int   astep = (g < 2) ? 512 : 0;
    const float* sqp  = ssq + g * 4;  // |c|^2 for this lane's 4 owned rows

    uint32_t A[16];
    #pragma unroll
    for (int i = 0; i < 16; ++i) A[i] = 0xFFFFFFFFu;

    const uint32_t gb2 = (uint32_t)(g << 2);

    for (int t0 = 0; t0 < 16; ++t0) {
        f32x4 acc[4], sqv[4];
        #pragma unroll
        for (int tt = 0; tt < 4; ++tt) {
            half8 af = *(const half8*)aptr; aptr += astep;
            sqv[tt] = *(const f32x4*)sqp;   sqp += 16;
            f32x4 z = {0.f, 0.f, 0.f, 0.f};
            acc[tt] = __builtin_amdgcn_mfma_f32_16x16x32_f16(af, bfrag, z, 0, 0, 0);
        }
        // Pack 16 keys: kf = |c|^2 - 2*dot (order == d2 order per query);
        // monotone uint transform (handles sign), low 10 bits = candidate idx.
        uint32_t B[16];
        const uint32_t basebits = ((uint32_t)t0 << 6) | gb2;
        #pragma unroll
        for (int tt = 0; tt < 4; ++tt) {
            #pragma unroll
            for (int v = 0; v < 4; ++v) {
                float kf = __builtin_fmaf(acc[tt][v], -2.0f, sqv[tt][v]);
                uint32_t u = __float_as_uint(kf);
                u ^= (uint32_t)(((int32_t)u) >> 31) | 0x80000000u;
                B[tt * 4 + v] = (u & 0xFFFFFC00u) | basebits | (uint32_t)((tt << 4) | v);
            }
        }
        // In-register bitonic sort-16 ascending (static indices, fully unrolled)
        #pragma unroll
        for (int k = 2; k <= 16; k <<= 1) {
            #pragma unroll
            for (int j = k >> 1; j > 0; j >>= 1) {
                #pragma unroll
                for (int i = 0; i < 16; ++i) {
                    int p = i ^ j;
                    if (p > i) {
                        uint32_t lo = umn(B[i], B[p]);
                        uint32_t hi = umx(B[i], B[p]);
                        bool up = ((i & k) == 0);
                        B[i] = up ? lo : hi;
                        B[p] = up ? hi : lo;
                    }
                }
            }
        }
        // Merge sorted B into sorted A (keep lower 16): half-cleaner + clean
        #pragma unroll
        for (int i = 0; i < 16; ++i) A[i] = umn(A[i], B[15 - i]);
        #pragma unroll
        for (int j = 8; j > 0; j >>= 1) {
            #pragma unroll
            for (int i = 0; i < 16; ++i) {
                int p = i ^ j;
                if (p > i) {
                    uint32_t lo = umn(A[i], A[p]);
                    uint32_t hi = umx(A[i], A[p]);
                    A[i] = lo; A[p] = hi;
                }
            }
        }
    }

    // Cross-lane merges: the 4 lanes (xor 16,32) owning this query converge
    // to the identical global sorted top-16.
    #pragma unroll
    for (int m = 16; m <= 32; m <<= 1) {
        uint32_t P[16];
        #pragma unroll
        for (int i = 0; i < 16; ++i) P[i] = __shfl_xor(A[15 - i], m, 64);
        #pragma unroll
        for (int i = 0; i < 16; ++i) A[i] = umn(A[i], P[i]);
        #pragma unroll
        for (int j = 8; j > 0; j >>= 1) {
            #pragma unroll
            for (int i = 0; i < 16; ++i) {
                int p = i ^ j;
                if (p > i) {
                    uint32_t lo = umn(A[i], A[p]);
                    uint32_t hi = umx(A[i], A[p]);
                    A[i] = lo; A[p] = hi;
                }
            }
        }
    }

    // Epilogue: each of the 4 lanes per query writes int4 #g of src and dst.
    const int base = seg * L_SEG;
    const int q    = base + qloc;
    uint32_t r[4];
    #pragma unroll
    for (int v = 0; v < 4; ++v) {  // select A[4g+v] without dynamic reg index
        uint32_t t01 = (g & 1) ? A[4 + v]  : A[v];
        uint32_t t23 = (g & 1) ? A[12 + v] : A[8 + v];
        r[v] = (g & 2) ? t23 : t01;
    }
    int4 sv;
    sv.x = base + (int)(r[0] & 1023u);
    sv.y = base + (int)(r[1] & 1023u);
    sv.z = base + (int)(r[2] & 1023u);
    sv.w = base + (int)(r[3] & 1023u);
    ((int4*)out)[(size_t)q * 4 + g] = sv;
    ((int4*)out)[(size_t)M_PTS * 4 + (size_t)q * 4 + g] = make_int4(q, q, q, q);
}

extern "C" void kernel_launch(void* const* d_in, const int* in_sizes, int n_in,
                              void* d_out, int out_size, void* d_ws, size_t ws_size,
                              hipStream_t stream) {
    const float* x = (const float*)d_in[0];
    // d_in[1] = segs (int64, all 1024) — static per problem setup, unused.
    int* out = (int*)d_out;
    knn_mfma_kernel<<<dim3(1024), dim3(256), 0, stream>>>(x, out);
}